// Round 6
// baseline (668.577 us; speedup 1.0000x reference)
//
#include <hip/hip_runtime.h>
#include <cmath>

#define NNODES 60000
#define DDIM   200
#define NCLS   250

constexpr int ROWS = 32;                     // rows per block -> 1875 blocks exact
constexpr int XP   = 216;                    // LDS pitch (shorts): 432B, 16B-aligned, ~2-way banks
constexpr int SH_SHORTS = 3 * ROWS * XP + 32;  // X | A | S | tail pad

typedef float  f32x4   __attribute__((ext_vector_type(4)));
typedef short  short8  __attribute__((ext_vector_type(8)));

// ---- ws layout: 14 uniform bf16 mats [256][224], zero-padded (rows>=ncols, k>=200)
constexpr int WM = 57344;                    // elems per mat
constexpr int M_P1C0 = 0, M_P1C1 = 1, M_P1C2 = 2, M_P2A = 3, M_P2B = 4,
              M_FX = 5, M_FH = 6, M_IX = 7, M_IH = 8, M_UX = 9, M_UH = 10,
              M_OX = 11, M_OH = 12, M_FC2 = 13;
constexpr int W_TOTAL_ELEMS = 14 * WM;       // 802816
constexpr size_t W_TOTAL_BYTES = (size_t)W_TOTAL_ELEMS * 2;   // 1,605,632 B

__device__ __forceinline__ short f2b(float f) {      // manual RNE (prepass)
    union { float f; unsigned u; } x; x.f = f;
    unsigned r = (x.u + 0x7FFFu + ((x.u >> 16) & 1u)) >> 16;
    return (short)r;
}
__device__ __forceinline__ unsigned cvtpk(float lo, float hi) {
    unsigned r; asm("v_cvt_pk_bf16_f32 %0, %1, %2" : "=v"(r) : "v"(lo), "v"(hi));
    return r;
}
__device__ __forceinline__ short f2b1(float f) { return (short)(cvtpk(f, f) & 0xffffu); }
__device__ __forceinline__ float b2f(short s) {
    union { unsigned u; float f; } x; x.u = ((unsigned)(unsigned short)s) << 16;
    return x.f;
}
__device__ __forceinline__ float b2f_lo(unsigned u) { return b2f((short)(u & 0xffffu)); }
__device__ __forceinline__ float b2f_hi(unsigned u) { return b2f((short)(u >> 16)); }
__device__ __forceinline__ float sgm(float x)  { return 1.0f / (1.0f + __expf(-x)); }
__device__ __forceinline__ float tanh_fast(float x) { return 1.0f - 2.0f / (__expf(2.0f * x) + 1.0f); }

// ================= weight prepass =================
__global__ void wprep(const float* __restrict__ p1w, const float* __restrict__ p2w,
                      const float* __restrict__ fxw, const float* __restrict__ fhw,
                      const float* __restrict__ ixw, const float* __restrict__ ihw,
                      const float* __restrict__ uxw, const float* __restrict__ uhw,
                      const float* __restrict__ oxw, const float* __restrict__ ohw,
                      const float* __restrict__ fc2w, short* __restrict__ ws)
{
    int i = blockIdx.x * 256 + threadIdx.x;
    if (i >= W_TOTAL_ELEMS) return;
    int m = i / WM, rem = i % WM;
    int n = rem / 224, k = rem % 224;
    const float* src; int stride = 200, off = 0, ncols = 200;
    switch (m) {
        case 0:  src = p1w;  stride = 600; off = 0;   break;
        case 1:  src = p1w;  stride = 600; off = 200; break;
        case 2:  src = p1w;  stride = 600; off = 400; break;
        case 3:  src = p2w;  stride = 400; off = 0;   break;
        case 4:  src = p2w;  stride = 400; off = 200; break;
        case 5:  src = fxw;  break;
        case 6:  src = fhw;  break;
        case 7:  src = ixw;  break;
        case 8:  src = ihw;  break;
        case 9:  src = uxw;  break;
        case 10: src = uhw;  break;
        case 11: src = oxw;  break;
        case 12: src = ohw;  break;
        default: src = fc2w; ncols = 250; break;
    }
    float v = 0.0f;
    if (n < ncols && k < 200) v = src[(long)n * stride + off + k];
    ws[i] = f2b(v);
}

// ================= GEMM pass: A from LDS, W from L2 (1-deep prefetch) =================
template<int NF>
__device__ __forceinline__ void passk(f32x4 (&acc)[NF], const short* __restrict__ Arow,
                                      const short* __restrict__ wmat, int nbase, int lg)
{
    const int kb = lg * 8;
    short8 a = *(const short8*)(Arow + kb);
    short8 w[NF], nw[NF];
    #pragma unroll
    for (int ni = 0; ni < NF; ++ni) w[ni] = *(const short8*)(wmat + (nbase + ni * 16) * 224 + kb);
    #pragma unroll 1
    for (int t = 0; t < 7; ++t) {
        const int kw = (t < 6) ? ((t + 1) * 32 + kb) : kb;    // t=6: dummy reload
        short8 na = *(const short8*)(Arow + kw);
        #pragma unroll
        for (int ni = 0; ni < NF; ++ni) nw[ni] = *(const short8*)(wmat + (nbase + ni * 16) * 224 + kw);
        #pragma unroll
        for (int ni = 0; ni < NF; ++ni)
            acc[ni] = __builtin_amdgcn_mfma_f32_16x16x32_bf16(a, w[ni], acc[ni], 0, 0, 0);
        a = na;
        #pragma unroll
        for (int ni = 0; ni < NF; ++ni) w[ni] = nw[ni];
    }
}

// ================= staging: 32 rows x 200 cols fp32 -> bf16 LDS =================
__device__ __forceinline__ void stage_chh(short* __restrict__ dst, const float* __restrict__ chh,
                                          int row0, int colofs, int tid)
{
    #pragma unroll
    for (int it = 0; it < 4; ++it) {
        int u = tid + it * 256;
        if (u < 800) {
            int r = u / 25, cu = (u % 25) * 8;
            const float* s = chh + (long)(row0 + r) * 800 + colofs + cu;
            float4 f0 = *(const float4*)s, f1 = *(const float4*)(s + 4);
            union { unsigned uu[4]; short8 ss; } c;
            c.uu[0] = cvtpk(f0.x, f0.y); c.uu[1] = cvtpk(f0.z, f0.w);
            c.uu[2] = cvtpk(f1.x, f1.y); c.uu[3] = cvtpk(f1.z, f1.w);
            *(short8*)(dst + r * XP + cu) = c.ss;
        }
    }
}
__device__ __forceinline__ void stage_x(short* __restrict__ dst, const float* __restrict__ emb,
                                        const int* __restrict__ tok, int row0, int tid)
{
    #pragma unroll
    for (int it = 0; it < 4; ++it) {
        int u = tid + it * 256;
        if (u < 800) {
            int r = u / 25, cu = (u % 25) * 8;
            const float* s = emb + (long)tok[row0 + r] * DDIM + cu;
            float4 f0 = *(const float4*)s, f1 = *(const float4*)(s + 4);
            union { unsigned uu[4]; short8 ss; } c;
            c.uu[0] = cvtpk(f0.x, f0.y); c.uu[1] = cvtpk(f0.z, f0.w);
            c.uu[2] = cvtpk(f1.x, f1.y); c.uu[3] = cvtpk(f1.z, f1.w);
            *(short8*)(dst + r * XP + cu) = c.ss;
        }
    }
}

#define ZERO7(A)  { _Pragma("unroll") for (int ni_=0; ni_<7; ++ni_) { _Pragma("unroll") for (int q_=0;q_<4;++q_) A[ni_][q_] = 0.0f; } }
#define ZERO8(A)  { _Pragma("unroll") for (int ni_=0; ni_<8; ++ni_) { _Pragma("unroll") for (int q_=0;q_<4;++q_) A[ni_][q_] = 0.0f; } }

__global__ __launch_bounds__(256, 3)
void fused_v3(const int* __restrict__ tok,
              const float* __restrict__ chc,
              const float* __restrict__ chh,
              const float* __restrict__ emb,
              const float* __restrict__ p1b_, const float* __restrict__ p2b_,
              const float* __restrict__ ixb, const float* __restrict__ ihb,
              const float* __restrict__ fxb, const float* __restrict__ fhb,
              const float* __restrict__ uxb, const float* __restrict__ uhb,
              const float* __restrict__ oxb, const float* __restrict__ ohb,
              const float* __restrict__ fc2b,
              const short* __restrict__ ws,
              float* __restrict__ out)
{
    __shared__ __align__(16) short SH[SH_SHORTS];
    short* X = SH;                      // x = emb[tok]
    short* A = SH + ROWS * XP;          // control -> hs
    short* S = SH + 2 * ROWS * XP;      // child chunks -> h

    const int tid = threadIdx.x;
    const int wv = tid >> 6, wm = wv >> 1, wn = wv & 1;
    const int l15 = tid & 15, lg = (tid & 63) >> 4;
    const int row0 = blockIdx.x * ROWS;
    const int nb7 = wn * 112 + l15;
    const int nb8 = wn * 128 + l15;

    // lane's A-row base offsets
    const short* Xrow = X + (wm * 16 + l15) * XP;
    const short* Arow = A + (wm * 16 + l15) * XP;
    const short* Srow = S + (wm * 16 + l15) * XP;

    // ---- zero arena (pads + pre-write reads must be finite/zero) ----
    {
        short8 z = (short8)0;
        short8* shv = (short8*)SH;
        #pragma unroll 1
        for (int i = tid; i < SH_SHORTS / 8; i += 256) shv[i] = z;
    }
    __syncthreads();

    // ---- stage x and child0 ----
    stage_x(X, emb, tok, row0, tid);
    stage_chh(S, chh, row0, 0, tid);
    __syncthreads();

    f32x4 accg[7];

    // ==== FX: fxr = x @ fx^T + b (bf16-packed regs) ====
    unsigned fxr_pk[7][2];
    ZERO7(accg);
    passk<7>(accg, Xrow, ws + M_FX * WM, nb7, lg);
    #pragma unroll
    for (int ni = 0; ni < 7; ++ni) {
        const int col = wn * 112 + ni * 16 + l15;
        const float b = (col < DDIM) ? fxb[col] : 0.0f;
        fxr_pk[ni][0] = cvtpk(accg[ni][0] + b, accg[ni][1] + b);
        fxr_pk[ni][1] = cvtpk(accg[ni][2] + b, accg[ni][3] + b);
    }

    // ==== P1: control = relu([ch0|ch1|ch2] @ p1^T + b), chunked over staged children ====
    f32x4 accp[7];
    ZERO7(accp);
    passk<7>(accp, Srow, ws + M_P1C0 * WM, nb7, lg);
    __syncthreads();
    stage_chh(S, chh, row0, 200, tid);
    __syncthreads();
    passk<7>(accp, Srow, ws + M_P1C1 * WM, nb7, lg);
    __syncthreads();
    stage_chh(S, chh, row0, 400, tid);
    __syncthreads();
    passk<7>(accp, Srow, ws + M_P1C2 * WM, nb7, lg);
    #pragma unroll
    for (int ni = 0; ni < 7; ++ni) {
        const int col = wn * 112 + ni * 16 + l15;
        if (col < DDIM) {
            const float b = p1b_[col];
            #pragma unroll
            for (int j = 0; j < 4; ++j) {
                const int lr = wm * 16 + lg * 4 + j;
                A[lr * XP + col] = f2b1(fmaxf(accp[ni][j] + b, 0.0f));
            }
        }
    }

    // ==== FH x4: csum = sum_c sigmoid(ch_c@fh^T + fhb + fx) * chc_c ====
    float csum[7][4];
    #pragma unroll
    for (int ni = 0; ni < 7; ++ni)
        #pragma unroll
        for (int j = 0; j < 4; ++j) csum[ni][j] = 0.0f;

    __syncthreads();                       // S(ch2) reads done
    stage_chh(S, chh, row0, 0, tid);       // ch0 again
    __syncthreads();                       // also publishes control in A

    #pragma unroll 1
    for (int c = 0; c < 4; ++c) {
        ZERO7(accg);
        passk<7>(accg, Srow, ws + M_FH * WM, nb7, lg);
        #pragma unroll
        for (int ni = 0; ni < 7; ++ni) {
            const int col = wn * 112 + ni * 16 + l15;
            if (col < DDIM) {
                const float fb = fhb[col];
                #pragma unroll
                for (int j = 0; j < 4; ++j) {
                    const int lr = wm * 16 + lg * 4 + j;
                    const float cv = chc[(long)(row0 + lr) * 800 + c * 200 + col];
                    const unsigned pk = fxr_pk[ni][j >> 1];
                    const float fx = (j & 1) ? b2f_hi(pk) : b2f_lo(pk);
                    csum[ni][j] += sgm(accg[ni][j] + fb + fx) * cv;
                }
            }
        }
        if (c < 3) {
            __syncthreads();
            stage_chh(S, chh, row0, (c + 1) * 200, tid);
            __syncthreads();
        }
    }

    // ==== P2: hs = relu(control@p2a^T + ch3@p2b^T + b) -> A (overwrite control) ====
    ZERO7(accg);
    passk<7>(accg, Arow, ws + M_P2A * WM, nb7, lg);
    passk<7>(accg, Srow, ws + M_P2B * WM, nb7, lg);
    __syncthreads();                       // all control reads done
    #pragma unroll
    for (int ni = 0; ni < 7; ++ni) {
        const int col = wn * 112 + ni * 16 + l15;
        if (col < DDIM) {
            const float b = p2b_[col];
            #pragma unroll
            for (int j = 0; j < 4; ++j) {
                const int lr = wm * 16 + lg * 4 + j;
                A[lr * XP + col] = f2b1(fmaxf(accg[ni][j] + b, 0.0f));
            }
        }
    }
    __syncthreads();                       // hs visible

    // ==== I gate ====
    unsigned gi_pk[7][2];
    ZERO7(accg);
    passk<7>(accg, Xrow, ws + M_IX * WM, nb7, lg);
    passk<7>(accg, Arow, ws + M_IH * WM, nb7, lg);
    #pragma unroll
    for (int ni = 0; ni < 7; ++ni) {
        const int col = wn * 112 + ni * 16 + l15;
        const float b = (col < DDIM) ? (ixb[col] + ihb[col]) : 0.0f;
        gi_pk[ni][0] = cvtpk(sgm(accg[ni][0] + b), sgm(accg[ni][1] + b));
        gi_pk[ni][1] = cvtpk(sgm(accg[ni][2] + b), sgm(accg[ni][3] + b));
    }

    // ==== U gate: csum <- i*tanh(u) + csum ====
    ZERO7(accg);
    passk<7>(accg, Xrow, ws + M_UX * WM, nb7, lg);
    passk<7>(accg, Arow, ws + M_UH * WM, nb7, lg);
    #pragma unroll
    for (int ni = 0; ni < 7; ++ni) {
        const int col = wn * 112 + ni * 16 + l15;
        const float b = (col < DDIM) ? (uxb[col] + uhb[col]) : 0.0f;
        #pragma unroll
        for (int j = 0; j < 4; ++j) {
            const unsigned pk = gi_pk[ni][j >> 1];
            const float gi = (j & 1) ? b2f_hi(pk) : b2f_lo(pk);
            csum[ni][j] = gi * tanh_fast(accg[ni][j] + b) + csum[ni][j];
        }
    }

    // ==== O gate; h = sigmoid(o)*tanh(c) -> S ====
    ZERO7(accg);
    passk<7>(accg, Xrow, ws + M_OX * WM, nb7, lg);
    passk<7>(accg, Arow, ws + M_OH * WM, nb7, lg);
    #pragma unroll
    for (int ni = 0; ni < 7; ++ni) {
        const int col = wn * 112 + ni * 16 + l15;
        if (col < DDIM) {
            const float b = oxb[col] + ohb[col];
            #pragma unroll
            for (int j = 0; j < 4; ++j) {
                const int lr = wm * 16 + lg * 4 + j;
                S[lr * XP + col] = f2b1(sgm(accg[ni][j] + b) * tanh_fast(csum[ni][j]));
            }
        }
    }
    __syncthreads();                       // h visible

    // ==== FC2: logits = h @ fc2^T + b -> out ====
    f32x4 acc8[8];
    ZERO8(acc8);
    passk<8>(acc8, Srow, ws + M_FC2 * WM, nb8, lg);
    #pragma unroll
    for (int ni = 0; ni < 8; ++ni) {
        const int col = wn * 128 + ni * 16 + l15;
        if (col < NCLS) {
            const float b = fc2b[col];
            #pragma unroll
            for (int j = 0; j < 4; ++j) {
                const int lr = wm * 16 + lg * 4 + j;
                out[(long)(row0 + lr) * NCLS + col] = acc8[ni][j] + b;
            }
        }
    }
}

// ================= fallback fp32 kernel (used only if ws too small) =================
constexpr int FRT = 32, FBK = 16, FNT = 256, FRTP = FRT + 4, FBUFP = 208;
__device__ __forceinline__ float sgm_f(float x) { return 1.0f / (1.0f + expf(-x)); }

__device__ __forceinline__ void f_stage(
    float (*aT)[FRTP], float (*wt)[FNT], int row0, int k0,
    const float* a1g, int a1pitch, const int* gidx, const float* a1l, int a1lp, int K1,
    const float* a2g, int a2pitch, const float* a2l, int a2lp, int K2,
    const float* wa, int wap, int KW1, const float* wb, int wbp,
    int ncols, int tid)
{
    const int Ktot = K1 + K2;
    {
        const int kk = tid & 15, k = k0 + kk;
        #pragma unroll
        for (int h = 0; h < 2; ++h) {
            const int r = (tid >> 4) + h * 16;
            float v = 0.0f;
            if (k < K1) {
                if (a1l) v = a1l[r * a1lp + k];
                else {
                    const long rb = gidx ? (long)gidx[row0 + r] * a1pitch : (long)(row0 + r) * a1pitch;
                    v = a1g[rb + k];
                }
            } else if (k < Ktot) {
                if (a2l) v = a2l[r * a2lp + (k - K1)];
                else     v = a2g[(long)(row0 + r) * a2pitch + (k - K1)];
            }
            aT[kk][r] = v;
        }
    }
    {
        const int col = tid;
        #pragma unroll
        for (int kk = 0; kk < FBK; ++kk) {
            const int k = k0 + kk; float v = 0.0f;
            if (col < ncols && k < Ktot) {
                if (k < KW1) v = wa[(long)col * wap + k];
                else         v = wb[(long)col * wbp + (k - KW1)];
            }
            wt[kk][col] = v;
        }
    }
}
__device__ __forceinline__ void f_gemm(
    float (*aT)[FRTP], float (*wt)[FNT], float acc[8][4], int row0,
    const float* a1g, int a1p, const int* gidx, const float* a1l, int a1lp, int K1,
    const float* a2g, int a2p, const float* a2l, int a2lp, int K2,
    const float* wa, int wap, int KW1, const float* wb, int wbp,
    int ncols, int tid, int tr, int tc)
{
    #pragma unroll
    for (int j = 0; j < 8; ++j)
        #pragma unroll
        for (int i = 0; i < 4; ++i) acc[j][i] = 0.0f;
    const int Ktot = K1 + K2;
    for (int k0 = 0; k0 < Ktot; k0 += FBK) {
        __syncthreads();
        f_stage(aT, wt, row0, k0, a1g, a1p, gidx, a1l, a1lp, K1, a2g, a2p, a2l, a2lp, K2,
                wa, wap, KW1, wb, wbp, ncols, tid);
        __syncthreads();
        #pragma unroll
        for (int kk = 0; kk < FBK; ++kk) {
            const float w0 = wt[kk][tc*4+0], w1 = wt[kk][tc*4+1], w2 = wt[kk][tc*4+2], w3 = wt[kk][tc*4+3];
            #pragma unroll
            for (int j = 0; j < 8; ++j) {
                const float a = aT[kk][tr*8+j];
                acc[j][0] = fmaf(a, w0, acc[j][0]); acc[j][1] = fmaf(a, w1, acc[j][1]);
                acc[j][2] = fmaf(a, w2, acc[j][2]); acc[j][3] = fmaf(a, w3, acc[j][3]);
            }
        }
    }
}
__global__ __launch_bounds__(256)
void fused_fp32(const int* tok, const float* chc, const float* chh, const float* emb,
                const float* p1w, const float* p1b, const float* p2w, const float* p2b,
                const float* ixw, const float* ixb, const float* ihw, const float* ihb,
                const float* fxw, const float* fxb, const float* fhw, const float* fhb,
                const float* uxw, const float* uxb, const float* uhw, const float* uhb,
                const float* oxw, const float* oxb, const float* ohw, const float* ohb,
                const float* fc2w, const float* fc2b, float* out)
{
    __shared__ float aT[FBK][FRTP]; __shared__ float wt[FBK][FNT]; __shared__ float buf[FRT][FBUFP];
    const int tid = threadIdx.x, tr = tid >> 6, tc = tid & 63, c0 = tc * 4;
    const int row0 = blockIdx.x * FRT;
    float acc[8][4];
    f_gemm(aT, wt, acc, row0, chh, 800, nullptr, nullptr, 0, 600, nullptr,0,nullptr,0,0, p1w,600,600,nullptr,0, DDIM, tid,tr,tc);
    if (c0 < DDIM) { const float4 b = *(const float4*)&p1b[c0];
        #pragma unroll
        for (int j=0;j<8;++j){int r=tr*8+j; buf[r][c0]=fmaxf(acc[j][0]+b.x,0.f); buf[r][c0+1]=fmaxf(acc[j][1]+b.y,0.f); buf[r][c0+2]=fmaxf(acc[j][2]+b.z,0.f); buf[r][c0+3]=fmaxf(acc[j][3]+b.w,0.f);} }
    f_gemm(aT, wt, acc, row0, nullptr,0,nullptr,&buf[0][0],FBUFP,200, chh+600,800,nullptr,0,200, p2w,400,400,nullptr,0, DDIM, tid,tr,tc);
    if (c0 < DDIM) { const float4 b = *(const float4*)&p2b[c0];
        #pragma unroll
        for (int j=0;j<8;++j){int r=tr*8+j; buf[r][c0]=fmaxf(acc[j][0]+b.x,0.f); buf[r][c0+1]=fmaxf(acc[j][1]+b.y,0.f); buf[r][c0+2]=fmaxf(acc[j][2]+b.z,0.f); buf[r][c0+3]=fmaxf(acc[j][3]+b.w,0.f);} }
    f_gemm(aT, wt, acc, row0, emb, DDIM, tok, nullptr,0,200, nullptr,0,nullptr,0,0, fxw,200,200,nullptr,0, DDIM, tid,tr,tc);
    float fxr[8][4];
    { float4 b = make_float4(0,0,0,0); if (c0<DDIM) b = *(const float4*)&fxb[c0];
      #pragma unroll
      for (int j=0;j<8;++j){fxr[j][0]=acc[j][0]+b.x;fxr[j][1]=acc[j][1]+b.y;fxr[j][2]=acc[j][2]+b.z;fxr[j][3]=acc[j][3]+b.w;} }
    float csum[8][4];
    #pragma unroll
    for (int j=0;j<8;++j)
        #pragma unroll
        for (int i=0;i<4;++i) csum[j][i]=0.f;
    for (int cc_=0; cc_<4; ++cc_) {
        f_gemm(aT, wt, acc, row0, chh+cc_*200,800,nullptr,nullptr,0,200, nullptr,0,nullptr,0,0, fhw,200,200,nullptr,0, DDIM, tid,tr,tc);
        if (c0 < DDIM) { const float4 b = *(const float4*)&fhb[c0];
            #pragma unroll
            for (int j=0;j<8;++j){ const long r=row0+tr*8+j; const float4 cv=*(const float4*)&chc[r*800+cc_*200+c0];
                csum[j][0]+=sgm_f(acc[j][0]+b.x+fxr[j][0])*cv.x; csum[j][1]+=sgm_f(acc[j][1]+b.y+fxr[j][1])*cv.y;
                csum[j][2]+=sgm_f(acc[j][2]+b.z+fxr[j][2])*cv.z; csum[j][3]+=sgm_f(acc[j][3]+b.w+fxr[j][3])*cv.w; } }
    }
    f_gemm(aT, wt, acc, row0, emb, DDIM, tok, nullptr,0,200, nullptr,0,&buf[0][0],FBUFP,200, ixw,200,200,ihw,200, DDIM, tid,tr,tc);
    float gi[8][4];
    { float4 b1=make_float4(0,0,0,0),b2=b1; if(c0<DDIM){b1=*(const float4*)&ixb[c0];b2=*(const float4*)&ihb[c0];}
      #pragma unroll
      for(int j=0;j<8;++j){gi[j][0]=sgm_f(acc[j][0]+b1.x+b2.x);gi[j][1]=sgm_f(acc[j][1]+b1.y+b2.y);gi[j][2]=sgm_f(acc[j][2]+b1.z+b2.z);gi[j][3]=sgm_f(acc[j][3]+b1.w+b2.w);} }
    f_gemm(aT, wt, acc, row0, emb, DDIM, tok, nullptr,0,200, nullptr,0,&buf[0][0],FBUFP,200, uxw,200,200,uhw,200, DDIM, tid,tr,tc);
    float cval[8][4];
    { float4 b1=make_float4(0,0,0,0),b2=b1; if(c0<DDIM){b1=*(const float4*)&uxb[c0];b2=*(const float4*)&uhb[c0];}
      #pragma unroll
      for(int j=0;j<8;++j){cval[j][0]=gi[j][0]*tanhf(acc[j][0]+b1.x+b2.x)+csum[j][0];cval[j][1]=gi[j][1]*tanhf(acc[j][1]+b1.y+b2.y)+csum[j][1];
                           cval[j][2]=gi[j][2]*tanhf(acc[j][2]+b1.z+b2.z)+csum[j][2];cval[j][3]=gi[j][3]*tanhf(acc[j][3]+b1.w+b2.w)+csum[j][3];} }
    f_gemm(aT, wt, acc, row0, emb, DDIM, tok, nullptr,0,200, nullptr,0,&buf[0][0],FBUFP,200, oxw,200,200,ohw,200, DDIM, tid,tr,tc);
    if (c0 < DDIM) { const float4 b1=*(const float4*)&oxb[c0], b2=*(const float4*)&ohb[c0];
        #pragma unroll
        for(int j=0;j<8;++j){int r=tr*8+j;
            buf[r][c0]=sgm_f(acc[j][0]+b1.x+b2.x)*tanhf(cval[j][0]); buf[r][c0+1]=sgm_f(acc[j][1]+b1.y+b2.y)*tanhf(cval[j][1]);
            buf[r][c0+2]=sgm_f(acc[j][2]+b1.z+b2.z)*tanhf(cval[j][2]); buf[r][c0+3]=sgm_f(acc[j][3]+b1.w+b2.w)*tanhf(cval[j][3]);} }
    f_gemm(aT, wt, acc, row0, nullptr,0,nullptr,&buf[0][0],FBUFP,200, nullptr,0,nullptr,0,0, fc2w,200,200,nullptr,0, NCLS, tid,tr,tc);
    #pragma unroll
    for (int j=0;j<8;++j){ const long r=row0+tr*8+j;
        #pragma unroll
        for (int i=0;i<4;++i){ const int col=c0+i; if (col<NCLS) out[r*NCLS+col]=acc[j][i]+fc2b[col]; } }
}

// ================= launch =================
extern "C" void kernel_launch(void* const* d_in, const int* in_sizes, int n_in,
                              void* d_out, int out_size, void* d_ws, size_t ws_size,
                              hipStream_t stream)
{
    const int*   tok  = (const int*)  d_in[0];
    const float* chc  = (const float*)d_in[1];
    const float* chh  = (const float*)d_in[2];
    const float* emb  = (const float*)d_in[3];
    const float* p1w  = (const float*)d_in[4];
    const float* p1b  = (const float*)d_in[5];
    const float* p2w  = (const float*)d_in[6];
    const float* p2b  = (const float*)d_in[7];
    const float* ixw  = (const float*)d_in[8];
    const float* ixb  = (const float*)d_in[9];
    const float* ihw  = (const float*)d_in[10];
    const float* ihb  = (const float*)d_in[11];
    const float* fxw  = (const float*)d_in[12];
    const float* fxb  = (const float*)d_in[13];
    const float* fhw  = (const float*)d_in[14];
    const float* fhb  = (const float*)d_in[15];
    const float* uxw  = (const float*)d_in[16];
    const float* uxb  = (const float*)d_in[17];
    const float* uhw  = (const float*)d_in[18];
    const float* uhb  = (const float*)d_in[19];
    const float* oxw  = (const float*)d_in[20];
    const float* oxb  = (const float*)d_in[21];
    const float* ohw  = (const float*)d_in[22];
    const float* ohb  = (const float*)d_in[23];
    const float* fc2w = (const float*)d_in[24];
    const float* fc2b = (const float*)d_in[25];
    float* out = (float*)d_out;

    if (ws_size >= W_TOTAL_BYTES) {
        short* ws = (short*)d_ws;
        hipLaunchKernelGGL(wprep, dim3((W_TOTAL_ELEMS + 255) / 256), dim3(256), 0, stream,
                           p1w, p2w, fxw, fhw, ixw, ihw, uxw, uhw, oxw, ohw, fc2w, ws);
        hipLaunchKernelGGL(fused_v3, dim3(NNODES / ROWS), dim3(256), 0, stream,
                           tok, chc, chh, emb,
                           p1b, p2b, ixb, ihb, fxb, fhb, uxb, uhb, oxb, ohb, fc2b,
                           ws, out);
    } else {
        hipLaunchKernelGGL(fused_fp32, dim3(NNODES / FRT), dim3(256), 0, stream,
                           tok, chc, chh, emb, p1w, p1b, p2w, p2b,
                           ixw, ixb, ihw, ihb, fxw, fxb, fhw, fhb,
                           uxw, uxb, uhw, uhb, oxw, oxb, ohw, ohb, fc2w, fc2b, out);
    }
}